// Round 1
// baseline (653.779 us; speedup 1.0000x reference)
//
#include <hip/hip_runtime.h>

#define NN 20000
#define EE 320000
#define CS 128
#define CV 16
#define CZ 64
#define CH 256

#define MIN_LD 488   // 480 padded K + 8 (odd multiple of 16B rows)
#define H_LD   264   // 256 + 8

typedef float f32x4 __attribute__((ext_vector_type(4)));
typedef __bf16 bf16x8 __attribute__((ext_vector_type(8)));
typedef unsigned short u16x8 __attribute__((ext_vector_type(8)));

__device__ inline unsigned short f2bf(float f) {
    union { float f; unsigned u; } v; v.f = f;
    unsigned u = v.u;
    return (unsigned short)((u + 0x7fffu + ((u >> 16) & 1u)) >> 16);
}

__device__ inline bf16x8 as_bf(u16x8 u) {
    union { u16x8 u; bf16x8 b; } c; c.u = u; return c.b;
}

// ---------------- weight prep: f32 [K][N] -> bf16 [N][K(padded)] ----------------
__global__ void prep_kernel(const float* __restrict__ W1, const float* __restrict__ W2,
                            const float* __restrict__ W3,
                            unsigned short* __restrict__ W1t, unsigned short* __restrict__ W2t,
                            unsigned short* __restrict__ W3t)
{
    int b = blockIdx.x, t = threadIdx.x;
    if (b < 480) {                       // W1: K=464 (pad to 480), N=256
        int k = b;
        float v = (k < 464) ? W1[(size_t)k * 256 + t] : 0.0f;
        W1t[(size_t)t * 480 + k] = f2bf(v);
    } else if (b < 736) {                // W2: 256x256
        int k = b - 480;
        W2t[(size_t)t * 256 + k] = f2bf(W2[(size_t)k * 256 + t]);
    } else {                             // W3: K=256, N=128
        int k = b - 736;
        if (t < 128) W3t[(size_t)t * 256 + k] = f2bf(W3[(size_t)k * 128 + t]);
    }
}

// ---------------- per-node: s_pts, vecs, out_s_v ----------------
__global__ void node_kernel(const float* __restrict__ ns, const float* __restrict__ nv,
                            const float* __restrict__ rot, const float* __restrict__ trans,
                            const float* __restrict__ W_pts, const float* __restrict__ b_pts,
                            const float* __restrict__ W_comb, const float* __restrict__ W_spts,
                            float* __restrict__ vecs, float* __restrict__ out_v)
{
    const int n = blockIdx.x;
    const int t = threadIdx.x;           // 64 threads
    __shared__ float s_ns[128];
    __shared__ float s_sp[24];
    __shared__ float s_vc[24 * 3];

    s_ns[t]      = ns[(size_t)n * CS + t];
    s_ns[64 + t] = ns[(size_t)n * CS + 64 + t];
    __syncthreads();

    if (t < 24) {                        // s_pts flat [24] = ns @ W_pts + b
        float a = b_pts[t];
        for (int c = 0; c < 128; ++c) a += s_ns[c] * W_pts[c * 24 + t];
        s_sp[t] = a;
    }
    if (t < 48) s_vc[t] = nv[(size_t)n * 48 + t];   // channels 0..15
    __syncthreads();

    if (t < 24) {                        // rotate points into global frame
        int p = t / 3, i = t % 3;
        // spl[p][j] = s_sp[j*8+p]; g[p][i] = sum_j rot[i][j]*spl[p][j]
        float g = rot[n * 9 + i * 3 + 0] * s_sp[0 * 8 + p]
                + rot[n * 9 + i * 3 + 1] * s_sp[1 * 8 + p]
                + rot[n * 9 + i * 3 + 2] * s_sp[2 * 8 + p];
        s_vc[(16 + p) * 3 + i] = g;
    }
    __syncthreads();

    if (t < 48) {                        // vecs = vc @ W_comb + trans/10 ; out_v = vc @ W_spts
        int v = t / 3, d = t % 3;
        float a = 0.0f, a2 = 0.0f;
        for (int c = 0; c < 24; ++c) {
            float x = s_vc[c * 3 + d];
            a  += x * W_comb[c * 16 + v];
            a2 += x * W_spts[c * 16 + v];
        }
        vecs[(size_t)n * 48 + v * 3 + d]  = a + trans[n * 3 + d] / 10.0f;
        out_v[(size_t)n * 48 + v * 3 + d] = a2;
    }
}

// ---------------- per-edge MLP (the big one) ----------------
__global__ __launch_bounds__(512, 1)
void edge_kernel(const float* __restrict__ ns, const float* __restrict__ ef,
                 const int* __restrict__ eidx, const float* __restrict__ rot,
                 const float* __restrict__ trans, const float* __restrict__ vecs,
                 const unsigned short* __restrict__ W1t, const unsigned short* __restrict__ W2t,
                 const unsigned short* __restrict__ W3t,
                 const float* __restrict__ b1, const float* __restrict__ b2,
                 const float* __restrict__ b3,
                 float* __restrict__ sums, float* __restrict__ cnt)
{
    __shared__ __align__(16) unsigned short s_min[64 * MIN_LD]; // m_in bf16, later reused for h2
    __shared__ __align__(16) unsigned short s_h1[64 * H_LD];
    __shared__ float s_rt[64 * 12];
    __shared__ int s_src[64];
    __shared__ int s_dst[64];

    const int tid = threadIdx.x;
    const int e0  = blockIdx.x * 64;

    if (tid < 64) {
        int s = eidx[e0 + tid];
        int d = eidx[EE + e0 + tid];
        s_src[tid] = s; s_dst[tid] = d;
        atomicAdd(&cnt[d], 1.0f);
        #pragma unroll
        for (int j = 0; j < 9; ++j) s_rt[tid * 12 + j] = rot[(size_t)d * 9 + j];
        #pragma unroll
        for (int j = 0; j < 3; ++j) s_rt[tid * 12 + 9 + j] = trans[(size_t)d * 3 + j];
    }
    __syncthreads();

    // ---- stage m_in [64][480] bf16: [ns_dst(128) | ns_src(128) | ef(64) | feats(144) | 0(16)]
    {
        const int e = tid >> 3, c8 = tid & 7;   // 8 threads per edge
        const int dI = s_dst[e], sI = s_src[e];
        const float* nsd = ns + (size_t)dI * CS;
        const float* nss = ns + (size_t)sI * CS;
        const float* efr = ef + (size_t)(e0 + e) * CZ;
        unsigned short* row = s_min + e * MIN_LD;
        #pragma unroll
        for (int q = 0; q < 10; ++q) {          // 40 scalar cols per thread
            int col = c8 * 40 + q * 4;
            const float* p = (col < 128) ? (nsd + col)
                            : (col < 256 ? nss + (col - 128) : efr + (col - 256));
            float4 v = *reinterpret_cast<const float4*>(p);
            row[col + 0] = f2bf(v.x); row[col + 1] = f2bf(v.y);
            row[col + 2] = f2bf(v.z); row[col + 3] = f2bf(v.w);
        }
        if (c8 == 0) {
            #pragma unroll
            for (int k = 464; k < 480; ++k) row[k] = 0;
        }
        // feats: 2 vector channels per thread
        const float* R = s_rt + e * 12;
        const float tx = R[9], ty = R[10], tz = R[11];
        #pragma unroll
        for (int cc = 0; cc < 2; ++cc) {
            int c = c8 * 2 + cc;
            const float* vd = vecs + ((size_t)dI * CV + c) * 3;
            const float* vs = vecs + ((size_t)sI * CV + c) * 3;
            float dx = vd[0] - tx, dy = vd[1] - ty, dz = vd[2] - tz;
            float sx = vs[0] - tx, sy = vs[1] - ty, sz = vs[2] - tz;
            // loc[i] = sum_j R[j][i] * w[j]   (R^T)
            float li0 = R[0]*dx + R[3]*dy + R[6]*dz;
            float li1 = R[1]*dx + R[4]*dy + R[7]*dz;
            float li2 = R[2]*dx + R[5]*dy + R[8]*dz;
            float lj0 = R[0]*sx + R[3]*sy + R[6]*sz;
            float lj1 = R[1]*sx + R[4]*sy + R[7]*sz;
            float lj2 = R[2]*sx + R[5]*sy + R[8]*sz;
            row[320 + c*3 + 0] = f2bf(li0);
            row[320 + c*3 + 1] = f2bf(li1);
            row[320 + c*3 + 2] = f2bf(li2);
            row[368 + c*3 + 0] = f2bf(lj0);
            row[368 + c*3 + 1] = f2bf(lj1);
            row[368 + c*3 + 2] = f2bf(lj2);
            row[416 + c*3 + 0] = f2bf(lj0 - li0);
            row[416 + c*3 + 1] = f2bf(lj1 - li1);
            row[416 + c*3 + 2] = f2bf(lj2 - li2);
        }
    }
    __syncthreads();

    // wave -> tile mapping: 8 waves = 2 (rows) x 4 (cols)
    const int w = tid >> 6, lane = tid & 63;
    const int wm = w >> 2, wn = w & 3;
    const int lr = lane & 15;
    const int lk = (lane >> 4) * 8;
    const int orow = (lane >> 4) * 4;   // C/D row base per lane

    // ---- layer 1: [64 x 480] @ [480 x 256] ----
    f32x4 acc[2][4];
    #pragma unroll
    for (int ni = 0; ni < 4; ++ni) {
        float bv = b1[wn * 64 + ni * 16 + lr];
        #pragma unroll
        for (int mi = 0; mi < 2; ++mi) acc[mi][ni] = f32x4{bv, bv, bv, bv};
    }
    #pragma unroll
    for (int ks = 0; ks < 15; ++ks) {
        const int k0 = ks * 32 + lk;
        bf16x8 a[2];
        #pragma unroll
        for (int mi = 0; mi < 2; ++mi)
            a[mi] = as_bf(*reinterpret_cast<const u16x8*>(&s_min[(wm*32 + mi*16 + lr) * MIN_LD + k0]));
        #pragma unroll
        for (int ni = 0; ni < 4; ++ni) {
            bf16x8 b = as_bf(*reinterpret_cast<const u16x8*>(W1t + (size_t)(wn*64 + ni*16 + lr) * 480 + k0));
            acc[0][ni] = __builtin_amdgcn_mfma_f32_16x16x32_bf16(a[0], b, acc[0][ni], 0, 0, 0);
            acc[1][ni] = __builtin_amdgcn_mfma_f32_16x16x32_bf16(a[1], b, acc[1][ni], 0, 0, 0);
        }
    }
    #pragma unroll
    for (int mi = 0; mi < 2; ++mi)
        #pragma unroll
        for (int ni = 0; ni < 4; ++ni)
            #pragma unroll
            for (int i = 0; i < 4; ++i)
                s_h1[(wm*32 + mi*16 + orow + i) * H_LD + wn*64 + ni*16 + lr] =
                    f2bf(fmaxf(acc[mi][ni][i], 0.0f));
    __syncthreads();

    // ---- layer 2: [64 x 256] @ [256 x 256] ----
    #pragma unroll
    for (int ni = 0; ni < 4; ++ni) {
        float bv = b2[wn * 64 + ni * 16 + lr];
        #pragma unroll
        for (int mi = 0; mi < 2; ++mi) acc[mi][ni] = f32x4{bv, bv, bv, bv};
    }
    #pragma unroll
    for (int ks = 0; ks < 8; ++ks) {
        const int k0 = ks * 32 + lk;
        bf16x8 a[2];
        #pragma unroll
        for (int mi = 0; mi < 2; ++mi)
            a[mi] = as_bf(*reinterpret_cast<const u16x8*>(&s_h1[(wm*32 + mi*16 + lr) * H_LD + k0]));
        #pragma unroll
        for (int ni = 0; ni < 4; ++ni) {
            bf16x8 b = as_bf(*reinterpret_cast<const u16x8*>(W2t + (size_t)(wn*64 + ni*16 + lr) * 256 + k0));
            acc[0][ni] = __builtin_amdgcn_mfma_f32_16x16x32_bf16(a[0], b, acc[0][ni], 0, 0, 0);
            acc[1][ni] = __builtin_amdgcn_mfma_f32_16x16x32_bf16(a[1], b, acc[1][ni], 0, 0, 0);
        }
    }
    // h2 -> s_min region (m_in is dead; all its reads were before the previous barrier)
    #pragma unroll
    for (int mi = 0; mi < 2; ++mi)
        #pragma unroll
        for (int ni = 0; ni < 4; ++ni)
            #pragma unroll
            for (int i = 0; i < 4; ++i)
                s_min[(wm*32 + mi*16 + orow + i) * H_LD + wn*64 + ni*16 + lr] =
                    f2bf(fmaxf(acc[mi][ni][i], 0.0f));
    __syncthreads();

    // ---- layer 3: [64 x 256] @ [256 x 128] ----
    f32x4 acc3[2][2];
    #pragma unroll
    for (int ni = 0; ni < 2; ++ni) {
        float bv = b3[wn * 32 + ni * 16 + lr];
        #pragma unroll
        for (int mi = 0; mi < 2; ++mi) acc3[mi][ni] = f32x4{bv, bv, bv, bv};
    }
    #pragma unroll
    for (int ks = 0; ks < 8; ++ks) {
        const int k0 = ks * 32 + lk;
        bf16x8 a[2];
        #pragma unroll
        for (int mi = 0; mi < 2; ++mi)
            a[mi] = as_bf(*reinterpret_cast<const u16x8*>(&s_min[(wm*32 + mi*16 + lr) * H_LD + k0]));
        #pragma unroll
        for (int ni = 0; ni < 2; ++ni) {
            bf16x8 b = as_bf(*reinterpret_cast<const u16x8*>(W3t + (size_t)(wn*32 + ni*16 + lr) * 256 + k0));
            acc3[0][ni] = __builtin_amdgcn_mfma_f32_16x16x32_bf16(a[0], b, acc3[0][ni], 0, 0, 0);
            acc3[1][ni] = __builtin_amdgcn_mfma_f32_16x16x32_bf16(a[1], b, acc3[1][ni], 0, 0, 0);
        }
    }
    // scatter msg into per-dst sums
    #pragma unroll
    for (int mi = 0; mi < 2; ++mi)
        #pragma unroll
        for (int ni = 0; ni < 2; ++ni)
            #pragma unroll
            for (int i = 0; i < 4; ++i) {
                int r  = wm*32 + mi*16 + orow + i;
                int cI = wn*32 + ni*16 + lr;
                atomicAdd(&sums[(size_t)s_dst[r] * CS + cI], acc3[mi][ni][i]);
            }
}

// ---------------- finalize: mean ----------------
__global__ void final_kernel(float* __restrict__ out, const float* __restrict__ cnt)
{
    int i = blockIdx.x * 256 + threadIdx.x;    // N*CS elements
    out[i] = out[i] / fmaxf(cnt[i >> 7], 1.0f);
}

extern "C" void kernel_launch(void* const* d_in, const int* in_sizes, int n_in,
                              void* d_out, int out_size, void* d_ws, size_t ws_size,
                              hipStream_t stream)
{
    const float* ns     = (const float*)d_in[0];
    const float* nv     = (const float*)d_in[1];
    const float* ef     = (const float*)d_in[2];
    const int*   eidx   = (const int*)  d_in[3];
    const float* rot    = (const float*)d_in[4];
    const float* trans  = (const float*)d_in[5];
    const float* W_pts  = (const float*)d_in[6];
    const float* b_pts  = (const float*)d_in[7];
    const float* W_comb = (const float*)d_in[8];
    const float* W_spts = (const float*)d_in[9];
    const float* W1     = (const float*)d_in[10];
    const float* b1     = (const float*)d_in[11];
    const float* W2     = (const float*)d_in[12];
    const float* b2     = (const float*)d_in[13];
    const float* W3     = (const float*)d_in[14];
    const float* b3     = (const float*)d_in[15];

    float* out   = (float*)d_out;
    float* sums  = out;                         // [N,128] accumulated in place
    float* out_v = out + (size_t)NN * CS;       // [N,16,3]

    char* ws = (char*)d_ws;
    size_t off = 0;
    float* cnt  = (float*)(ws + off); off += ((size_t)NN * 4 + 255) & ~255ull;
    float* vecs = (float*)(ws + off); off += ((size_t)NN * 48 * 4 + 255) & ~255ull;
    unsigned short* W1t = (unsigned short*)(ws + off); off += ((size_t)256 * 480 * 2 + 255) & ~255ull;
    unsigned short* W2t = (unsigned short*)(ws + off); off += ((size_t)256 * 256 * 2 + 255) & ~255ull;
    unsigned short* W3t = (unsigned short*)(ws + off);

    hipMemsetAsync(sums, 0, (size_t)NN * CS * 4, stream);
    hipMemsetAsync(cnt,  0, (size_t)NN * 4, stream);

    prep_kernel<<<992, 256, 0, stream>>>(W1, W2, W3, W1t, W2t, W3t);
    node_kernel<<<NN, 64, 0, stream>>>(ns, nv, rot, trans, W_pts, b_pts, W_comb, W_spts, vecs, out_v);
    edge_kernel<<<EE / 64, 512, 0, stream>>>(ns, ef, eidx, rot, trans, vecs,
                                             W1t, W2t, W3t, b1, b2, b3, sums, cnt);
    final_kernel<<<(NN * CS) / 256, 256, 0, stream>>>(out, cnt);
}